// Round 9
// baseline (650.045 us; speedup 1.0000x reference)
//
#include <hip/hip_runtime.h>
#include <hip/hip_bf16.h>

#define D 128
#define SCAN_C 512
#define BKT 512        // nodes per bucket
#define BKT_SHIFT 9
#define CH 256         // edge chunks
#define NBMAX 512
#define MREP 64        // min-buffer replicas
#define NSLICE 8       // column slices of x: 32 B (16 bf16) per row per slice

typedef __attribute__((ext_vector_type(8))) short bf16x8;
typedef __attribute__((ext_vector_type(4))) float f32x4;

// ---------------- bf16 helpers (manual, RN-even) ----------------
__device__ __forceinline__ float bf16_to_f(unsigned int u) {
    union { unsigned int i; float f; } c; c.i = u << 16; return c.f;
}
__device__ __forceinline__ unsigned short f_to_bf16(float f) {
    union { float f; unsigned int i; } c; c.f = f;
    unsigned int r = c.i + 0x7FFFu + ((c.i >> 16) & 1u);
    return (unsigned short)(r >> 16);
}

__device__ __forceinline__ int load_idx(const void* p, long long i, int is64) {
    if (is64) return (int)((const long long*)p)[i];
    return ((const int*)p)[i];
}

// ---------------- wave-parallel dtype detection (runs inline in any block) ----------------
__device__ __forceinline__ void detect_inline(const void* x0, const void* eidx,
                                              int* is_bf16_out, int* is64_out) {
    const unsigned short* xr = (const unsigned short*)x0;
    const int* er = (const int*)eidx;
    const int lane = threadIdx.x & 63;
    unsigned short u = xr[2 * lane];
    int e = (u >> 7) & 0xFF;
    unsigned long long pm = __ballot(e >= 0x74 && e <= 0x82);
    *is_bf16_out = (__popcll(pm) >= 32) ? 1 : 0;
    unsigned long long zm = __ballot(er[1 + 2 * lane] == 0);
    *is64_out = (__popcll(zm) >= 60) ? 1 : 0;
}

// ---------------- merged setup: detect + cvt_x(sliced) + hist + cvt_f + minbuf + packW ------
// Sliced x layout: slice s holds shorts [s*16, s*16+16) of each row, at
// xs[s*SP + node*16 + c], SP = N*16 shorts (3.2 MB per slice -> fits one XCD L2).
__global__ __launch_bounds__(256)
void setup_kernel(const void* __restrict__ x0, const void* __restrict__ eidx,
                  const void* __restrict__ Wl0, const void* __restrict__ Wr0,
                  const void* __restrict__ bl0,
                  int* __restrict__ flag, unsigned short* __restrict__ xb,
                  float* __restrict__ blf, unsigned short* __restrict__ Wpack,
                  int* __restrict__ counts2D, unsigned int* __restrict__ minbuf,
                  int N, int E, int L, int NB, int EPC) {
    __shared__ int hist[NBMAX];
    int is_bf16, is64;
    detect_inline(x0, eidx, &is_bf16, &is64);
    const int b = blockIdx.x;
    const int t = threadIdx.x;
    if (b == 0 && t == 0) { flag[0] = is64; flag[1] = is_bf16; }
    const size_t SP = (size_t)N * 16;

    if (b < 2048) {                       // cvt_x -> sliced bf16 (always materialized)
        const int totalHalf = N * 16;     // 16-B units
        for (int i = b * 256 + t; i < totalHalf; i += 2048 * 256) {
            int node = i >> 4;
            int so = (i & 15) * 8;        // short offset in row (s*16 + half*8)
            unsigned short o[8];
            if (is_bf16) {
                const unsigned short* s2 = (const unsigned short*)x0 + (size_t)node * D + so;
                *(uint4*)o = *(const uint4*)s2;
            } else {
                const float* s4 = (const float*)x0 + (size_t)node * D + so;
#pragma unroll
                for (int j = 0; j < 8; ++j) o[j] = f_to_bf16(s4[j]);
            }
            int sl = so >> 4;
            int half = (so >> 3) & 1;
            *(uint4*)&xb[sl * SP + (size_t)node * 16 + half * 8] = *(uint4*)o;
        }
        return;
    }
    if (b < 2048 + CH) {                  // bucket hist
        const int c = b - 2048;
        for (int i = t; i < NB; i += 256) hist[i] = 0;
        __syncthreads();
        const int end = min(E, (c + 1) * EPC);
        for (int e = c * EPC + t; e < end; e += 256) {
            int d = load_idx(eidx, (long long)E + e, is64);
            atomicAdd(&hist[d >> BKT_SHIFT], 1);
        }
        __syncthreads();
        for (int i = t; i < NB; i += 256) counts2D[i * CH + c] = hist[i];
        return;
    }
    if (b == 2048 + CH) {                 // cvt_f (bias)
        const int n = L * D;
        if (is_bf16) {
            const unsigned short* s = (const unsigned short*)bl0;
            for (int i = t; i < n; i += 256) blf[i] = bf16_to_f(s[i]);
        } else {
            const float* s = (const float*)bl0;
            for (int i = t; i < n; i += 256) blf[i] = s[i];
        }
        return;
    }
    if (b == 2048 + CH + 1) {             // minbuf init
        for (int i = t; i < MREP * D; i += 256) minbuf[i] = 0xFFFFFFFFu;
        return;
    }
    // packW
    {
        int idx = (b - (2048 + CH + 2)) * 256 + t;
        if (idx >= L * 8 * 8 * 64) return;
        int lane = idx & 63;
        int ks = (idx >> 6) & 7;
        int nt = (idx >> 9) & 7;
        int layer = idx >> 12;
        int n = nt * 16 + (lane & 15);
        int k0 = ks * 32 + (lane >> 4) * 8;
        unsigned short outv[8];
#pragma unroll
        for (int j = 0; j < 8; ++j) {
            int k = k0 + j;
            size_t off = (size_t)layer * D * D + (size_t)n * D + (k & 127);
            float v;
            if (is_bf16) {
                const unsigned short* W = (const unsigned short*)((k < D) ? Wl0 : Wr0);
                v = bf16_to_f(W[off]);
            } else {
                const float* W = (const float*)((k < D) ? Wl0 : Wr0);
                v = W[off];
            }
            outv[j] = f_to_bf16(v);
        }
        *(uint4*)&Wpack[(size_t)idx * 8] = *(uint4*)outv;
    }
}

// ---------------- 3-kernel scan cascade (known-good) ----------
__global__ void gscan1_kernel(const int* __restrict__ in, int* __restrict__ blockSums, int n) {
    __shared__ int red[256];
    int base = blockIdx.x * SCAN_C;
    int t = threadIdx.x;
    int s = 0;
    if (base + t < n) s += in[base + t];
    if (base + t + 256 < n) s += in[base + t + 256];
    red[t] = s;
    __syncthreads();
    for (int off = 128; off > 0; off >>= 1) {
        if (t < off) red[t] += red[t + off];
        __syncthreads();
    }
    if (t == 0) blockSums[blockIdx.x] = red[0];
}

__global__ void gscan2_kernel(int* __restrict__ blockSums, int nb) {
    __shared__ int sh[256];
    int t = threadIdx.x;
    int orig = (t < nb) ? blockSums[t] : 0;
    sh[t] = orig;
    __syncthreads();
    for (int off = 1; off < 256; off <<= 1) {
        int v = (t >= off) ? sh[t - off] : 0;
        __syncthreads();
        sh[t] += v;
        __syncthreads();
    }
    if (t < nb) blockSums[t] = sh[t] - orig;
}

__global__ void gscan3_kernel(const int* __restrict__ in, const int* __restrict__ blockBase,
                              int* __restrict__ out, int n) {
    __shared__ int sh[SCAN_C];
    int base = blockIdx.x * SCAN_C;
    int t = threadIdx.x;
    int v0 = (base + t < n) ? in[base + t] : 0;
    int v1 = (base + t + 256 < n) ? in[base + t + 256] : 0;
    sh[t] = v0;
    sh[t + 256] = v1;
    __syncthreads();
    for (int off = 1; off < SCAN_C; off <<= 1) {
        int a = (t >= off) ? sh[t - off] : 0;
        int b = (t + 256 >= off) ? sh[t + 256 - off] : 0;
        __syncthreads();
        sh[t] += a;
        sh[t + 256] += b;
        __syncthreads();
    }
    int bb = blockBase[blockIdx.x];
    if (base + t < n) out[base + t] = bb + sh[t] - v0;
    if (base + t + 256 < n) out[base + t + 256] = bb + sh[t + 256] - v1;
}

__global__ void bucket_scatter_kernel(const void* __restrict__ eidx, const int* __restrict__ flag,
                                      const int* __restrict__ bases2D, unsigned int* __restrict__ ebuf,
                                      int E, int NB, int EPC) {
    __shared__ int cur[NBMAX];
    int c = blockIdx.x;
    for (int i = threadIdx.x; i < NB; i += blockDim.x) cur[i] = bases2D[i * CH + c];
    __syncthreads();
    int is64 = flag[0];
    int end = min(E, (c + 1) * EPC);
    for (int e = c * EPC + threadIdx.x; e < end; e += blockDim.x) {
        int s = load_idx(eidx, e, is64);
        int d = load_idx(eidx, (long long)E + e, is64);
        int b = d >> BKT_SHIFT;
        int pos = atomicAdd(&cur[b], 1);
        ebuf[pos] = ((unsigned)s << BKT_SHIFT) | (unsigned)(d & (BKT - 1));
    }
}

__global__ __launch_bounds__(BKT)
void bucket_csr_kernel(const unsigned int* __restrict__ ebuf, const int* __restrict__ bases2D,
                       int* __restrict__ offsets, int* __restrict__ srcs, int E, int N, int NB) {
    __shared__ int lcnt[BKT];
    __shared__ int sh[BKT];
    __shared__ int lcur[BKT];
    int b = blockIdx.x;
    int t = threadIdx.x;
    int start = bases2D[b * CH];
    int end = (b + 1 < NB) ? bases2D[(b + 1) * CH] : E;
    lcnt[t] = 0;
    __syncthreads();
    for (int e = start + t; e < end; e += BKT)
        atomicAdd(&lcnt[ebuf[e] & (BKT - 1)], 1);
    __syncthreads();
    sh[t] = lcnt[t];
    __syncthreads();
    for (int off = 1; off < BKT; off <<= 1) {
        int v = (t >= off) ? sh[t - off] : 0;
        __syncthreads();
        sh[t] += v;
        __syncthreads();
    }
    int excl = sh[t] - lcnt[t];
    int node = b * BKT + t;
    if (node < N) offsets[node] = start + excl;
    lcur[t] = start + excl;
    __syncthreads();
    for (int e = start + t; e < end; e += BKT) {
        unsigned int p = ebuf[e];
        int pos = atomicAdd(&lcur[p & (BKT - 1)], 1);
        srcs[pos] = (int)(p >> BKT_SHIFT);
    }
    if (b == 0 && t == 0) offsets[N] = E;
}

// ---------------- XCD-sliced mean aggregation ----------------
// slice = blockIdx & 7 -> round-robin dispatch pins slice s to XCD s; the 3.2 MB
// slice stays resident in that XCD's 4 MB L2, turning random gathers into L2 hits.
// 16-lane group per node: lanes split (sub = gl>>3) across an edge PAIR, dw = gl&7
// indexes the 8 dwords of the 32-B slice chunk. 16-edge unroll = 8 loads in flight.
__global__ void agg_kernel(const unsigned short* __restrict__ xs,
                           const int* __restrict__ offsets,
                           const int* __restrict__ srcs,
                           unsigned short* __restrict__ means, int N) {
    const int sl = blockIdx.x & 7;
    const int nodeblk = blockIdx.x >> 3;
    const int g = threadIdx.x >> 4;          // 0..15
    const int gl = threadIdx.x & 15;
    const int sub = gl >> 3;                 // edge-of-pair
    const int dw = gl & 7;                   // dword within 32-B chunk
    const size_t SP = (size_t)N * 16;
    const unsigned int* x32 = (const unsigned int*)(xs + sl * SP);
    unsigned int* m32 = (unsigned int*)(means + sl * SP);

#define ACC1(u) { a0 += bf16_to_f((u) & 0xFFFFu); a1 += bf16_to_f((u) >> 16); }
    for (int i = 0; i < 4; ++i) {
        const int node = nodeblk * 64 + g * 4 + i;
        if (node >= N) return;               // uniform within 16-lane group
        const int beg = offsets[node], end = offsets[node + 1];
        float a0 = 0.f, a1 = 0.f;
        int j = beg;
        for (; j + 15 < end; j += 16) {
            int i0 = srcs[j + 0 + sub];  int i1 = srcs[j + 2 + sub];
            int i2 = srcs[j + 4 + sub];  int i3 = srcs[j + 6 + sub];
            int i4 = srcs[j + 8 + sub];  int i5 = srcs[j + 10 + sub];
            int i6 = srcs[j + 12 + sub]; int i7 = srcs[j + 14 + sub];
            unsigned u0 = x32[(size_t)i0 * 8 + dw];
            unsigned u1 = x32[(size_t)i1 * 8 + dw];
            unsigned u2 = x32[(size_t)i2 * 8 + dw];
            unsigned u3 = x32[(size_t)i3 * 8 + dw];
            unsigned u4 = x32[(size_t)i4 * 8 + dw];
            unsigned u5 = x32[(size_t)i5 * 8 + dw];
            unsigned u6 = x32[(size_t)i6 * 8 + dw];
            unsigned u7 = x32[(size_t)i7 * 8 + dw];
            ACC1(u0); ACC1(u1); ACC1(u2); ACC1(u3);
            ACC1(u4); ACC1(u5); ACC1(u6); ACC1(u7);
        }
        for (; j + 1 < end; j += 2) {
            unsigned u = x32[(size_t)srcs[j + sub] * 8 + dw];
            ACC1(u);
        }
        if (j < end && sub == 0) {           // odd tail edge
            unsigned u = x32[(size_t)srcs[j] * 8 + dw];
            ACC1(u);
        }
        a0 += __shfl_xor(a0, 8, 64);         // combine pair halves (same dw)
        a1 += __shfl_xor(a1, 8, 64);
        if (sub == 0) {
            float inv = (end > beg) ? 1.0f / (float)(end - beg) : 0.f;
            m32[(size_t)node * 8 + dw] =
                (unsigned)f_to_bf16(a0 * inv) | ((unsigned)f_to_bf16(a1 * inv) << 16);
        }
    }
#undef ACC1
}

// ---------------- MFMA dual GEMM, W staged in LDS; sliced A operands ----------------
// A-fragment (m16, quad) wants row shorts [sigma, sigma+8), sigma = ks*32 + quad*8.
// In sliced layout: slice = sigma>>4 = 2*ks + (quad>>1), offset = (quad&1)*8. 16-B aligned.
__global__ __launch_bounds__(512)
void gemm_mfma_kernel(const unsigned short* __restrict__ means,
                      const unsigned short* __restrict__ xs,
                      const unsigned short* __restrict__ Wpack, const float* __restrict__ bl,
                      unsigned short* __restrict__ outb, unsigned int* __restrict__ minbuf,
                      int N, int relu, int do_min) {
    __shared__ unsigned short Wlds[8 * 8 * 64 * 8];   // 64 KB; aliased as Otile in epilogue
    __shared__ float smin[8][D];

    const int tid = threadIdx.x;
    const int wave = tid >> 6;            // 0..7
    const int lane = tid & 63;
    const int m16 = lane & 15;
    const int quad = lane >> 4;
    const int node0 = blockIdx.x * 128;
    const int arow = node0 + wave * 16 + m16;
    const bool rvalid = arow < N;
    const size_t SP = (size_t)N * 16;

    {
        const uint4* wsrc = (const uint4*)Wpack;
        uint4* wdst = (uint4*)Wlds;
#pragma unroll
        for (int i = 0; i < 8; ++i) wdst[tid + i * 512] = wsrc[tid + i * 512];
    }
    __syncthreads();

    f32x4 acc[8];
#pragma unroll
    for (int i = 0; i < 8; ++i) acc[i] = (f32x4)0.0f;

#pragma unroll
    for (int ks = 0; ks < 8; ++ks) {
        uint4 tmp = make_uint4(0u, 0u, 0u, 0u);
        if (rvalid) {
            const unsigned short* base = (ks < 4)
                ? means + (2 * ks + (quad >> 1)) * SP + (size_t)arow * 16 + (quad & 1) * 8
                : xs    + (2 * (ks - 4) + (quad >> 1)) * SP + (size_t)arow * 16 + (quad & 1) * 8;
            tmp = *(const uint4*)base;
        }
        bf16x8 afrag = *(bf16x8*)&tmp;
#pragma unroll
        for (int nt = 0; nt < 8; ++nt) {
            bf16x8 bfrag = *(const bf16x8*)&Wlds[((nt * 8 + ks) * 64 + lane) * 8];
            acc[nt] = __builtin_amdgcn_mfma_f32_16x16x32_bf16(afrag, bfrag, acc[nt], 0, 0, 0);
        }
    }

    if (do_min) {
#pragma unroll
        for (int nt = 0; nt < 8; ++nt) {
            int n = nt * 16 + m16;
            float b = bl[n];
            float m = 3.402823466e38f;
#pragma unroll
            for (int r = 0; r < 4; ++r) {
                int node = node0 + wave * 16 + quad * 4 + r;
                float v = (node < N) ? (acc[nt][r] + b) : 3.402823466e38f;
                m = fminf(m, v);
            }
            m = fminf(m, __shfl_xor(m, 16, 64));
            m = fminf(m, __shfl_xor(m, 32, 64));
            if (quad == 0) smin[wave][n] = m;
        }
        __syncthreads();
        if (tid < D) {
            float m = smin[0][tid];
#pragma unroll
            for (int w = 1; w < 8; ++w) m = fminf(m, smin[w][tid]);
            unsigned bits = __float_as_uint(m);
            unsigned enc = ((int)bits >= 0) ? (bits ^ 0x80000000u) : ~bits;
            atomicMin(&minbuf[(blockIdx.x & (MREP - 1)) * D + tid], enc);
        }
        return;
    }

    __syncthreads();   // all ds_reads of Wlds complete before aliasing as Otile
    {
        unsigned short (*Ot)[136] = (unsigned short (*)[136])Wlds;   // 128x136
#pragma unroll
        for (int nt = 0; nt < 8; ++nt) {
            int n = nt * 16 + m16;
            float b = bl[n];
#pragma unroll
            for (int r = 0; r < 4; ++r) {
                int m = wave * 16 + quad * 4 + r;
                float v = acc[nt][r] + b;
                if (relu) v = fmaxf(v, 0.f);
                Ot[m][n] = f_to_bf16(v);
            }
        }
        __syncthreads();
        // sliced writeout: per wave, 64 consecutive (row,half) units within one slice
        for (int k = tid; k < 128 * 16; k += 512) {
            int sl = k >> 8;             // 0..7
            int ws = k & 255;
            int row = ws >> 1;
            int half = ws & 1;
            int n = node0 + row;
            if (n < N)
                *(uint4*)&outb[sl * SP + (size_t)n * 16 + half * 8] =
                    *(uint4*)&Ot[row][sl * 16 + half * 8];
        }
    }
}

// ---------------- decode fused min (parallel replica fold) ----------------
__global__ void min_out_kernel(const unsigned int* __restrict__ minbuf,
                               const int* __restrict__ flag, void* __restrict__ out) {
    __shared__ unsigned int sh[4][D];
    int tid = threadIdx.x;             // 512 threads
    int q = tid >> 7;
    int c = tid & 127;
    unsigned u = 0xFFFFFFFFu;
    for (int r = q; r < MREP; r += 4) u = min(u, minbuf[r * D + c]);
    sh[q][c] = u;
    __syncthreads();
    if (tid < D) {
        unsigned m = min(min(sh[0][tid], sh[1][tid]), min(sh[2][tid], sh[3][tid]));
        unsigned i = (m & 0x80000000u) ? (m ^ 0x80000000u) : ~m;
        union { unsigned i; float f; } cv; cv.i = i;
        if (flag[1]) ((unsigned short*)out)[tid] = f_to_bf16(cv.f);
        else         ((float*)out)[tid] = cv.f;
    }
}

// ---------------- launch ----------------
extern "C" void kernel_launch(void* const* d_in, const int* in_sizes, int n_in,
                              void* d_out, int out_size, void* d_ws, size_t ws_size,
                              hipStream_t stream) {
    const void* x0   = d_in[0];
    const void* eidx = d_in[1];
    const void* Wl0  = d_in[2];
    const void* bl0  = d_in[3];
    const void* Wr0  = d_in[4];

    const int N = in_sizes[0] / D;          // 100000
    const int E = in_sizes[1] / 2;          // 1600000
    const int L = in_sizes[2] / (D * D);    // 3

    char* ws = (char*)d_ws;
    size_t off = 0;
    auto alloc = [&](size_t bytes) -> void* {
        void* p = ws + off;
        off += (bytes + 255) & ~(size_t)255;
        return p;
    };
    unsigned short* xb    = (unsigned short*)alloc((size_t)N * D * 2);   // sliced x (layer in)
    unsigned short* bufA  = (unsigned short*)alloc((size_t)N * D * 2);   // sliced layer out
    unsigned short* meanb = (unsigned short*)alloc((size_t)N * D * 2);   // sliced mean; ebuf alias
    int*   offsets = (int*)alloc((size_t)(N + 1) * sizeof(int));
    int*   srcs    = (int*)alloc((size_t)E * sizeof(int));
    int*   flag    = (int*)alloc(256);
    unsigned short* Wpack = (unsigned short*)alloc((size_t)L * 8 * 8 * 64 * 8 * 2);
    float* blf     = (float*)alloc((size_t)L * D * sizeof(float));
    unsigned int* minbuf = (unsigned int*)alloc((size_t)MREP * D * sizeof(unsigned int));
    int* counts2D  = (int*)alloc((size_t)NBMAX * CH * sizeof(int));
    int* bases2D   = (int*)alloc((size_t)NBMAX * CH * sizeof(int));
    int* blockSums = (int*)alloc(1024 * sizeof(int));
    (void)ws_size; (void)n_in; (void)out_size;

    const int NB  = (N + BKT - 1) / BKT;     // 196
    const int EPC = (E + CH - 1) / CH;       // 6250
    const int n2  = NB * CH;                 // 50176
    unsigned int* ebuf = (unsigned int*)meanb;   // not live during CSR build

    const int PACKW_BLOCKS = (L * 8 * 8 * 64 + 255) / 256;   // 48
    setup_kernel<<<2048 + CH + 2 + PACKW_BLOCKS, 256, 0, stream>>>(
        x0, eidx, Wl0, Wr0, bl0, flag, xb, blf, Wpack, counts2D, minbuf, N, E, L, NB, EPC);

    const int nb2 = (n2 + SCAN_C - 1) / SCAN_C;
    gscan1_kernel<<<nb2, 256, 0, stream>>>(counts2D, blockSums, n2);
    gscan2_kernel<<<1, 256, 0, stream>>>(blockSums, nb2);
    gscan3_kernel<<<nb2, 256, 0, stream>>>(counts2D, blockSums, bases2D, n2);
    bucket_scatter_kernel<<<CH, 256, 0, stream>>>(eidx, flag, bases2D, ebuf, E, NB, EPC);
    bucket_csr_kernel<<<NB, BKT, 0, stream>>>(ebuf, bases2D, offsets, srcs, E, N, NB);

    const unsigned short* cur = xb;          // always the sliced copy
    unsigned short* nxt = bufA;
    for (int l = 0; l < L; ++l) {
        int last = (l == L - 1);
        int agg_blocks = ((N + 63) / 64) * NSLICE;
        agg_kernel<<<agg_blocks, 256, 0, stream>>>(cur, offsets, srcs, meanb, N);
        gemm_mfma_kernel<<<(N + 127) / 128, 512, 0, stream>>>(
            meanb, cur, Wpack + (size_t)l * 8 * 8 * 64 * 8, blf + (size_t)l * D,
            nxt, minbuf, N, last ? 0 : 1, last);
        cur = nxt;
        nxt = (nxt == bufA) ? xb : bufA;
    }

    min_out_kernel<<<1, 512, 0, stream>>>(minbuf, flag, (void*)d_out);
}

// Round 13
// 375.267 us; speedup vs baseline: 1.7322x; 1.7322x over previous
//
#include <hip/hip_runtime.h>
#include <hip/hip_bf16.h>

#define D 128
#define SCAN_C 512
#define BKT 512        // nodes per bucket
#define BKT_SHIFT 9
#define CH 256         // edge chunks
#define NBMAX 512
#define MREP 64        // min-buffer replicas

typedef __attribute__((ext_vector_type(8))) short bf16x8;
typedef __attribute__((ext_vector_type(4))) float f32x4;

// ---------------- bf16 helpers (manual, RN-even) ----------------
__device__ __forceinline__ float bf16_to_f(unsigned int u) {
    union { unsigned int i; float f; } c; c.i = u << 16; return c.f;
}
__device__ __forceinline__ unsigned short f_to_bf16(float f) {
    union { float f; unsigned int i; } c; c.f = f;
    unsigned int r = c.i + 0x7FFFu + ((c.i >> 16) & 1u);
    return (unsigned short)(r >> 16);
}

__device__ __forceinline__ int load_idx(const void* p, long long i, int is64) {
    if (is64) return (int)((const long long*)p)[i];
    return ((const int*)p)[i];
}

// ---------------- wave-parallel dtype detection (runs inline in any block) ----------------
__device__ __forceinline__ void detect_inline(const void* x0, const void* eidx,
                                              int* is_bf16_out, int* is64_out) {
    const unsigned short* xr = (const unsigned short*)x0;
    const int* er = (const int*)eidx;
    const int lane = threadIdx.x & 63;
    unsigned short u = xr[2 * lane];
    int e = (u >> 7) & 0xFF;
    unsigned long long pm = __ballot(e >= 0x74 && e <= 0x82);
    *is_bf16_out = (__popcll(pm) >= 32) ? 1 : 0;
    unsigned long long zm = __ballot(er[1 + 2 * lane] == 0);
    *is64_out = (__popcll(zm) >= 60) ? 1 : 0;
}

// ---------------- merged setup: detect + cvt_x + hist + cvt_f + minbuf-init + packW ----------
// (r8-verified.) Role by blockIdx: [0,2048) cvt_x, [2048,2048+CH) hist,
// [2048+CH] cvt_f, [2048+CH+1] minbuf init, rest packW.
__global__ __launch_bounds__(256)
void setup_kernel(const void* __restrict__ x0, const void* __restrict__ eidx,
                  const void* __restrict__ Wl0, const void* __restrict__ Wr0,
                  const void* __restrict__ bl0,
                  int* __restrict__ flag, unsigned short* __restrict__ xb,
                  float* __restrict__ blf, unsigned short* __restrict__ Wpack,
                  int* __restrict__ counts2D, unsigned int* __restrict__ minbuf,
                  int N, int E, int L, int NB, int EPC) {
    __shared__ int hist[NBMAX];
    int is_bf16, is64;
    detect_inline(x0, eidx, &is_bf16, &is64);
    const int b = blockIdx.x;
    const int t = threadIdx.x;
    if (b == 0 && t == 0) { flag[0] = is64; flag[1] = is_bf16; }

    if (b < 2048) {                       // cvt_x
        if (!is_bf16) {
            const float* s = (const float*)x0;
            const int n = N * D;
            for (int i = b * 256 + t; i < n; i += 2048 * 256) xb[i] = f_to_bf16(s[i]);
        }
        return;
    }
    if (b < 2048 + CH) {                  // bucket hist
        const int c = b - 2048;
        for (int i = t; i < NB; i += 256) hist[i] = 0;
        __syncthreads();
        const int end = min(E, (c + 1) * EPC);
        for (int e = c * EPC + t; e < end; e += 256) {
            int d = load_idx(eidx, (long long)E + e, is64);
            atomicAdd(&hist[d >> BKT_SHIFT], 1);
        }
        __syncthreads();
        for (int i = t; i < NB; i += 256) counts2D[i * CH + c] = hist[i];
        return;
    }
    if (b == 2048 + CH) {                 // cvt_f (bias)
        const int n = L * D;
        if (is_bf16) {
            const unsigned short* s = (const unsigned short*)bl0;
            for (int i = t; i < n; i += 256) blf[i] = bf16_to_f(s[i]);
        } else {
            const float* s = (const float*)bl0;
            for (int i = t; i < n; i += 256) blf[i] = s[i];
        }
        return;
    }
    if (b == 2048 + CH + 1) {             // minbuf init (replaces hipMemsetAsync)
        for (int i = t; i < MREP * D; i += 256) minbuf[i] = 0xFFFFFFFFu;
        return;
    }
    // packW
    {
        int idx = (b - (2048 + CH + 2)) * 256 + t;
        if (idx >= L * 8 * 8 * 64) return;
        int lane = idx & 63;
        int ks = (idx >> 6) & 7;
        int nt = (idx >> 9) & 7;
        int layer = idx >> 12;
        int n = nt * 16 + (lane & 15);
        int k0 = ks * 32 + (lane >> 4) * 8;
        unsigned short outv[8];
#pragma unroll
        for (int j = 0; j < 8; ++j) {
            int k = k0 + j;
            size_t off = (size_t)layer * D * D + (size_t)n * D + (k & 127);
            float v;
            if (is_bf16) {
                const unsigned short* W = (const unsigned short*)((k < D) ? Wl0 : Wr0);
                v = bf16_to_f(W[off]);
            } else {
                const float* W = (const float*)((k < D) ? Wl0 : Wr0);
                v = W[off];
            }
            outv[j] = f_to_bf16(v);
        }
        *(uint4*)&Wpack[(size_t)idx * 8] = *(uint4*)outv;
    }
}

// ---------------- 3-kernel scan cascade (known-good) ----------
__global__ void gscan1_kernel(const int* __restrict__ in, int* __restrict__ blockSums, int n) {
    __shared__ int red[256];
    int base = blockIdx.x * SCAN_C;
    int t = threadIdx.x;
    int s = 0;
    if (base + t < n) s += in[base + t];
    if (base + t + 256 < n) s += in[base + t + 256];
    red[t] = s;
    __syncthreads();
    for (int off = 128; off > 0; off >>= 1) {
        if (t < off) red[t] += red[t + off];
        __syncthreads();
    }
    if (t == 0) blockSums[blockIdx.x] = red[0];
}

__global__ void gscan2_kernel(int* __restrict__ blockSums, int nb) {
    __shared__ int sh[256];
    int t = threadIdx.x;
    int orig = (t < nb) ? blockSums[t] : 0;
    sh[t] = orig;
    __syncthreads();
    for (int off = 1; off < 256; off <<= 1) {
        int v = (t >= off) ? sh[t - off] : 0;
        __syncthreads();
        sh[t] += v;
        __syncthreads();
    }
    if (t < nb) blockSums[t] = sh[t] - orig;
}

__global__ void gscan3_kernel(const int* __restrict__ in, const int* __restrict__ blockBase,
                              int* __restrict__ out, int n) {
    __shared__ int sh[SCAN_C];
    int base = blockIdx.x * SCAN_C;
    int t = threadIdx.x;
    int v0 = (base + t < n) ? in[base + t] : 0;
    int v1 = (base + t + 256 < n) ? in[base + t + 256] : 0;
    sh[t] = v0;
    sh[t + 256] = v1;
    __syncthreads();
    for (int off = 1; off < SCAN_C; off <<= 1) {
        int a = (t >= off) ? sh[t - off] : 0;
        int b = (t + 256 >= off) ? sh[t + 256 - off] : 0;
        __syncthreads();
        sh[t] += a;
        sh[t + 256] += b;
        __syncthreads();
    }
    int bb = blockBase[blockIdx.x];
    if (base + t < n) out[base + t] = bb + sh[t] - v0;
    if (base + t + 256 < n) out[base + t + 256] = bb + sh[t + 256] - v1;
}

__global__ void bucket_scatter_kernel(const void* __restrict__ eidx, const int* __restrict__ flag,
                                      const int* __restrict__ bases2D, unsigned int* __restrict__ ebuf,
                                      int E, int NB, int EPC) {
    __shared__ int cur[NBMAX];
    int c = blockIdx.x;
    for (int i = threadIdx.x; i < NB; i += blockDim.x) cur[i] = bases2D[i * CH + c];
    __syncthreads();
    int is64 = flag[0];
    int end = min(E, (c + 1) * EPC);
    for (int e = c * EPC + threadIdx.x; e < end; e += blockDim.x) {
        int s = load_idx(eidx, e, is64);
        int d = load_idx(eidx, (long long)E + e, is64);
        int b = d >> BKT_SHIFT;
        int pos = atomicAdd(&cur[b], 1);
        ebuf[pos] = ((unsigned)s << BKT_SHIFT) | (unsigned)(d & (BKT - 1));
    }
}

__global__ __launch_bounds__(BKT)
void bucket_csr_kernel(const unsigned int* __restrict__ ebuf, const int* __restrict__ bases2D,
                       int* __restrict__ offsets, int* __restrict__ srcs, int E, int N, int NB) {
    __shared__ int lcnt[BKT];
    __shared__ int sh[BKT];
    __shared__ int lcur[BKT];
    int b = blockIdx.x;
    int t = threadIdx.x;
    int start = bases2D[b * CH];
    int end = (b + 1 < NB) ? bases2D[(b + 1) * CH] : E;
    lcnt[t] = 0;
    __syncthreads();
    for (int e = start + t; e < end; e += BKT)
        atomicAdd(&lcnt[ebuf[e] & (BKT - 1)], 1);
    __syncthreads();
    sh[t] = lcnt[t];
    __syncthreads();
    for (int off = 1; off < BKT; off <<= 1) {
        int v = (t >= off) ? sh[t - off] : 0;
        __syncthreads();
        sh[t] += v;
        __syncthreads();
    }
    int excl = sh[t] - lcnt[t];
    int node = b * BKT + t;
    if (node < N) offsets[node] = start + excl;
    lcur[t] = start + excl;
    __syncthreads();
    for (int e = start + t; e < end; e += BKT) {
        unsigned int p = ebuf[e];
        int pos = atomicAdd(&lcur[p & (BKT - 1)], 1);
        srcs[pos] = (int)(p >> BKT_SHIFT);
    }
    if (b == 0 && t == 0) offsets[N] = E;
}

// ---------------- mean aggregation (r5/r8 proven; DO NOT TOUCH) ----------------
__global__ void agg_kernel(const unsigned short* __restrict__ xmain,
                           const unsigned short* __restrict__ xalt,
                           const int* __restrict__ flag, const int* __restrict__ offsets,
                           const int* __restrict__ srcs, unsigned short* __restrict__ meanb, int N) {
    const unsigned short* xb = flag[1] ? xalt : xmain;
    int g = blockIdx.x * blockDim.x + threadIdx.x;
    int node = g >> 4;
    int lane = g & 15;
    if (node >= N) return;
    int beg = offsets[node], end = offsets[node + 1];
    float acc[8];
#pragma unroll
    for (int i = 0; i < 8; ++i) acc[i] = 0.f;
    const uint4* xp = (const uint4*)xb;

#define ACC8(v)                                                              \
    acc[0] += bf16_to_f((v).x & 0xFFFFu); acc[1] += bf16_to_f((v).x >> 16);  \
    acc[2] += bf16_to_f((v).y & 0xFFFFu); acc[3] += bf16_to_f((v).y >> 16);  \
    acc[4] += bf16_to_f((v).z & 0xFFFFu); acc[5] += bf16_to_f((v).z >> 16);  \
    acc[6] += bf16_to_f((v).w & 0xFFFFu); acc[7] += bf16_to_f((v).w >> 16);

    int j = beg;
    for (; j + 7 < end; j += 8) {
        int s0 = srcs[j];     int s1 = srcs[j + 1];
        int s2 = srcs[j + 2]; int s3 = srcs[j + 3];
        int s4 = srcs[j + 4]; int s5 = srcs[j + 5];
        int s6 = srcs[j + 6]; int s7 = srcs[j + 7];
        uint4 v0 = xp[(size_t)s0 * 16 + lane];
        uint4 v1 = xp[(size_t)s1 * 16 + lane];
        uint4 v2 = xp[(size_t)s2 * 16 + lane];
        uint4 v3 = xp[(size_t)s3 * 16 + lane];
        uint4 v4 = xp[(size_t)s4 * 16 + lane];
        uint4 v5 = xp[(size_t)s5 * 16 + lane];
        uint4 v6 = xp[(size_t)s6 * 16 + lane];
        uint4 v7 = xp[(size_t)s7 * 16 + lane];
        ACC8(v0); ACC8(v1); ACC8(v2); ACC8(v3);
        ACC8(v4); ACC8(v5); ACC8(v6); ACC8(v7);
    }
    if (j + 3 < end) {
        int s0 = srcs[j];     int s1 = srcs[j + 1];
        int s2 = srcs[j + 2]; int s3 = srcs[j + 3];
        uint4 v0 = xp[(size_t)s0 * 16 + lane];
        uint4 v1 = xp[(size_t)s1 * 16 + lane];
        uint4 v2 = xp[(size_t)s2 * 16 + lane];
        uint4 v3 = xp[(size_t)s3 * 16 + lane];
        ACC8(v0); ACC8(v1); ACC8(v2); ACC8(v3);
        j += 4;
    }
    for (; j < end; ++j) {
        uint4 v = xp[(size_t)srcs[j] * 16 + lane];
        ACC8(v);
    }
#undef ACC8

    float inv = (end > beg) ? 1.0f / (float)(end - beg) : 0.0f;
    uint4 o;
    o.x = (unsigned)f_to_bf16(acc[0] * inv) | ((unsigned)f_to_bf16(acc[1] * inv) << 16);
    o.y = (unsigned)f_to_bf16(acc[2] * inv) | ((unsigned)f_to_bf16(acc[3] * inv) << 16);
    o.z = (unsigned)f_to_bf16(acc[4] * inv) | ((unsigned)f_to_bf16(acc[5] * inv) << 16);
    o.w = (unsigned)f_to_bf16(acc[6] * inv) | ((unsigned)f_to_bf16(acc[7] * inv) << 16);
    ((uint4*)meanb)[(size_t)node * 16 + lane] = o;
}

// ---------------- MFMA dual GEMM: 256 rows/block, W staged once ----------------
// vs r8 (128 rows): same 64 KB W stage amortized over 2x output -> W traffic
// 50->25 MB, 391 blocks, 128 MFMA/wave per stage, B-frag LDS reads halved per MFMA.
// Each wave owns rows {wave*16+m16} and {128+wave*16+m16}. Epilogue streams the
// 256x128 output in two 128-row chunks through the 34.8 KB Ot alias of Wlds.
__global__ __launch_bounds__(512)
void gemm_mfma_kernel(const unsigned short* __restrict__ meanb,
                      const unsigned short* __restrict__ xmain,
                      const unsigned short* __restrict__ xalt,
                      const int* __restrict__ flag,
                      const unsigned short* __restrict__ Wpack, const float* __restrict__ bl,
                      unsigned short* __restrict__ outb, unsigned int* __restrict__ minbuf,
                      int N, int relu, int do_min) {
    __shared__ unsigned short Wlds[8 * 8 * 64 * 8];   // 64 KB; aliased as Otile in epilogue
    __shared__ float smin[8][D];
    const unsigned short* xb = flag[1] ? xalt : xmain;

    const int tid = threadIdx.x;
    const int wave = tid >> 6;            // 0..7
    const int lane = tid & 63;
    const int m16 = lane & 15;
    const int quad = lane >> 4;
    const int node0 = blockIdx.x * 256;
    const int arow0 = node0 + wave * 16 + m16;
    const int arow1 = arow0 + 128;
    const bool rv0 = arow0 < N;
    const bool rv1 = arow1 < N;

    {
        const uint4* wsrc = (const uint4*)Wpack;
        uint4* wdst = (uint4*)Wlds;
#pragma unroll
        for (int i = 0; i < 8; ++i) wdst[tid + i * 512] = wsrc[tid + i * 512];
    }
    __syncthreads();

    f32x4 accA[8], accB[8];
#pragma unroll
    for (int i = 0; i < 8; ++i) { accA[i] = (f32x4)0.0f; accB[i] = (f32x4)0.0f; }

#pragma unroll
    for (int ks = 0; ks < 8; ++ks) {
        const int coff = (ks < 4) ? ks * 32 + quad * 8 : (ks - 4) * 32 + quad * 8;
        const unsigned short* src = (ks < 4) ? meanb : xb;
        uint4 t0 = make_uint4(0u, 0u, 0u, 0u);
        uint4 t1 = make_uint4(0u, 0u, 0u, 0u);
        if (rv0) t0 = *(const uint4*)(src + (size_t)arow0 * D + coff);
        if (rv1) t1 = *(const uint4*)(src + (size_t)arow1 * D + coff);
        bf16x8 a0 = *(bf16x8*)&t0;
        bf16x8 a1 = *(bf16x8*)&t1;
#pragma unroll
        for (int nt = 0; nt < 8; ++nt) {
            bf16x8 bfrag = *(const bf16x8*)&Wlds[((nt * 8 + ks) * 64 + lane) * 8];
            accA[nt] = __builtin_amdgcn_mfma_f32_16x16x32_bf16(a0, bfrag, accA[nt], 0, 0, 0);
            accB[nt] = __builtin_amdgcn_mfma_f32_16x16x32_bf16(a1, bfrag, accB[nt], 0, 0, 0);
        }
    }

    if (do_min) {
#pragma unroll
        for (int nt = 0; nt < 8; ++nt) {
            int n = nt * 16 + m16;
            float b = bl[n];
            float m = 3.402823466e38f;
#pragma unroll
            for (int r = 0; r < 4; ++r) {
                int nodeA = node0 + wave * 16 + quad * 4 + r;
                float vA = (nodeA < N) ? (accA[nt][r] + b) : 3.402823466e38f;
                m = fminf(m, vA);
                int nodeB = nodeA + 128;
                float vB = (nodeB < N) ? (accB[nt][r] + b) : 3.402823466e38f;
                m = fminf(m, vB);
            }
            m = fminf(m, __shfl_xor(m, 16, 64));
            m = fminf(m, __shfl_xor(m, 32, 64));
            if (quad == 0) smin[wave][n] = m;
        }
        __syncthreads();
        if (tid < D) {
            float m = smin[0][tid];
#pragma unroll
            for (int w = 1; w < 8; ++w) m = fminf(m, smin[w][tid]);
            unsigned bits = __float_as_uint(m);
            unsigned enc = ((int)bits >= 0) ? (bits ^ 0x80000000u) : ~bits;
            atomicMin(&minbuf[(blockIdx.x & (MREP - 1)) * D + tid], enc);
        }
        return;
    }

    __syncthreads();   // all ds_reads of Wlds complete before aliasing as Otile
    {
        unsigned short (*Ot)[136] = (unsigned short (*)[136])Wlds;   // 128x136 = 34.8 KB
        // ---- chunk 0: rows [node0, node0+128) from accA ----
#pragma unroll
        for (int nt = 0; nt < 8; ++nt) {
            int n = nt * 16 + m16;
            float b = bl[n];
#pragma unroll
            for (int r = 0; r < 4; ++r) {
                int m = wave * 16 + quad * 4 + r;
                float v = accA[nt][r] + b;
                if (relu) v = fmaxf(v, 0.f);
                Ot[m][n] = f_to_bf16(v);
            }
        }
        __syncthreads();
        for (int i = tid; i < 128 * 16; i += 512) {
            int row = i >> 4;
            int c = i & 15;
            int n = node0 + row;
            if (n < N) ((uint4*)outb)[(size_t)n * 16 + c] = *(uint4*)&Ot[row][c * 8];
        }
        __syncthreads();
        // ---- chunk 1: rows [node0+128, node0+256) from accB ----
#pragma unroll
        for (int nt = 0; nt < 8; ++nt) {
            int n = nt * 16 + m16;
            float b = bl[n];
#pragma unroll
            for (int r = 0; r < 4; ++r) {
                int m = wave * 16 + quad * 4 + r;
                float v = accB[nt][r] + b;
                if (relu) v = fmaxf(v, 0.f);
                Ot[m][n] = f_to_bf16(v);
            }
        }
        __syncthreads();
        for (int i = tid; i < 128 * 16; i += 512) {
            int row = i >> 4;
            int c = i & 15;
            int n = node0 + 128 + row;
            if (n < N) ((uint4*)outb)[(size_t)n * 16 + c] = *(uint4*)&Ot[row][c * 8];
        }
    }
}

// ---------------- decode fused min (parallel replica fold) ----------------
__global__ void min_out_kernel(const unsigned int* __restrict__ minbuf,
                               const int* __restrict__ flag, void* __restrict__ out) {
    __shared__ unsigned int sh[4][D];
    int tid = threadIdx.x;             // 512 threads
    int q = tid >> 7;
    int c = tid & 127;
    unsigned u = 0xFFFFFFFFu;
    for (int r = q; r < MREP; r += 4) u = min(u, minbuf[r * D + c]);
    sh[q][c] = u;
    __syncthreads();
    if (tid < D) {
        unsigned m = min(min(sh[0][tid], sh[1][tid]), min(sh[2][tid], sh[3][tid]));
        unsigned i = (m & 0x80000000u) ? (m ^ 0x80000000u) : ~m;
        union { unsigned i; float f; } cv; cv.i = i;
        if (flag[1]) ((unsigned short*)out)[tid] = f_to_bf16(cv.f);
        else         ((float*)out)[tid] = cv.f;
    }
}

// ---------------- launch ----------------
extern "C" void kernel_launch(void* const* d_in, const int* in_sizes, int n_in,
                              void* d_out, int out_size, void* d_ws, size_t ws_size,
                              hipStream_t stream) {
    const void* x0   = d_in[0];
    const void* eidx = d_in[1];
    const void* Wl0  = d_in[2];
    const void* bl0  = d_in[3];
    const void* Wr0  = d_in[4];

    const int N = in_sizes[0] / D;          // 100000
    const int E = in_sizes[1] / 2;          // 1600000
    const int L = in_sizes[2] / (D * D);    // 3

    char* ws = (char*)d_ws;
    size_t off = 0;
    auto alloc = [&](size_t bytes) -> void* {
        void* p = ws + off;
        off += (bytes + 255) & ~(size_t)255;
        return p;
    };
    unsigned short* xb    = (unsigned short*)alloc((size_t)N * D * 2);
    unsigned short* bufA  = (unsigned short*)alloc((size_t)N * D * 2);
    unsigned short* meanb = (unsigned short*)alloc((size_t)N * D * 2);   // ebuf aliased
    int*   offsets = (int*)alloc((size_t)(N + 1) * sizeof(int));
    int*   srcs    = (int*)alloc((size_t)E * sizeof(int));
    int*   flag    = (int*)alloc(256);
    unsigned short* Wpack = (unsigned short*)alloc((size_t)L * 8 * 8 * 64 * 8 * 2);
    float* blf     = (float*)alloc((size_t)L * D * sizeof(float));
    unsigned int* minbuf = (unsigned int*)alloc((size_t)MREP * D * sizeof(unsigned int));
    int* counts2D  = (int*)alloc((size_t)NBMAX * CH * sizeof(int));
    int* bases2D   = (int*)alloc((size_t)NBMAX * CH * sizeof(int));
    int* blockSums = (int*)alloc(1024 * sizeof(int));
    (void)ws_size; (void)n_in; (void)out_size;

    const int NB  = (N + BKT - 1) / BKT;     // 196
    const int EPC = (E + CH - 1) / CH;       // 6250
    const int n2  = NB * CH;                 // 50176
    unsigned int* ebuf = (unsigned int*)meanb;   // not live during CSR build

    const int PACKW_BLOCKS = (L * 8 * 8 * 64 + 255) / 256;   // 48
    setup_kernel<<<2048 + CH + 2 + PACKW_BLOCKS, 256, 0, stream>>>(
        x0, eidx, Wl0, Wr0, bl0, flag, xb, blf, Wpack, counts2D, minbuf, N, E, L, NB, EPC);

    const int nb2 = (n2 + SCAN_C - 1) / SCAN_C;
    gscan1_kernel<<<nb2, 256, 0, stream>>>(counts2D, blockSums, n2);
    gscan2_kernel<<<1, 256, 0, stream>>>(blockSums, nb2);
    gscan3_kernel<<<nb2, 256, 0, stream>>>(counts2D, blockSums, bases2D, n2);
    bucket_scatter_kernel<<<CH, 256, 0, stream>>>(eidx, flag, bases2D, ebuf, E, NB, EPC);
    bucket_csr_kernel<<<NB, BKT, 0, stream>>>(ebuf, bases2D, offsets, srcs, E, N, NB);

    const unsigned short* cur     = xb;                        // fp32 path: converted copy
    const unsigned short* cur_alt = (const unsigned short*)x0; // bf16 path: raw input
    unsigned short* nxt = bufA;
    for (int l = 0; l < L; ++l) {
        int last = (l == L - 1);
        int agg_blocks = (N * 16 + 255) / 256;
        agg_kernel<<<agg_blocks, 256, 0, stream>>>(cur, cur_alt, flag, offsets, srcs, meanb, N);
        gemm_mfma_kernel<<<(N + 255) / 256, 512, 0, stream>>>(
            meanb, cur, cur_alt, flag, Wpack + (size_t)l * 8 * 8 * 64 * 8, blf + (size_t)l * D,
            nxt, minbuf, N, last ? 0 : 1, last);
        cur = nxt; cur_alt = nxt;
        nxt = (nxt == bufA) ? xb : bufA;
    }

    min_out_kernel<<<1, 512, 0, stream>>>(minbuf, flag, (void*)d_out);
}